// Round 1
// baseline (39111.673 us; speedup 1.0000x reference)
//
#include <hip/hip_runtime.h>
#include <cstdint>

#define TT 1024
#define BB 128
#define DD 512
#define HH 256
#define TBR (TT*BB)   // 131072 rows

__device__ __forceinline__ float sigf(float x) { return 1.0f / (1.0f + expf(-x)); }

// ---------------------------------------------------------------------------
// Pack gate weights: wx_p[r][k] = W_gate[h][k] (input half), wh_p[r][k] =
// W_gate[h][256+k] (recurrent half), r = gate*256 + h, gates = {f,i,g,o}.
// ---------------------------------------------------------------------------
__global__ __launch_bounds__(256) void pack_kernel(
    const float* __restrict__ fw, const float* __restrict__ iw,
    const float* __restrict__ uw, const float* __restrict__ ow,
    const float* __restrict__ fb, const float* __restrict__ ib,
    const float* __restrict__ ub, const float* __restrict__ obb,
    float* __restrict__ wx_p, float* __restrict__ wh_p, float* __restrict__ b_p)
{
    const int r = blockIdx.x;            // 0..1023
    const int gate = r >> 8, h = r & 255;
    const float* wsrc = gate == 0 ? fw : gate == 1 ? iw : gate == 2 ? uw : ow;
    const float* bsrc = gate == 0 ? fb : gate == 1 ? ib : gate == 2 ? ub : obb;
    const int k = threadIdx.x;           // 0..255
    wx_p[(size_t)r * 256 + k] = wsrc[(size_t)h * 512 + k];
    wh_p[(size_t)r * 256 + k] = wsrc[(size_t)h * 512 + 256 + k];
    if (k == 0) b_p[r] = bsrc[h];
}

// ---------------------------------------------------------------------------
// Generic fp32 GEMM: C[m][n] = act(dot(A[m][:K], W[n][:K]) + bias[n]).
// 128x128 tile, 256 threads, 8x8 register frags. Frags stored in LDS as
// groups of 8 padded to 12 floats (keeps b128 reads 2-way conflict = free).
// PERM=1 permutes the output column for the xg layout (see recur_kernel).
// ---------------------------------------------------------------------------
template<int K, int ACT, int PERM>
__global__ __launch_bounds__(256) void gemm_kernel(
    const float* A, const float* __restrict__ W,
    const float* __restrict__ bias, float* C, int N)
{
    __shared__ __align__(16) float As[16][192];
    __shared__ __align__(16) float Wt[16][192];
    const int tid = threadIdx.x;
    const int m0 = blockIdx.x * 128, n0 = blockIdx.y * 128;
    const int tm = tid >> 4, tn = tid & 15;
    const int am = tm * 12, wn = tn * 12;
    float acc[8][8] = {};
    for (int kc = 0; kc < K; kc += 16) {
        #pragma unroll
        for (int i = 0; i < 2; ++i) {
            int f4 = tid + 256 * i;              // 0..511
            int r = f4 >> 2, k4 = (f4 & 3) * 4;
            float4 av = *(const float4*)&A[(size_t)(m0 + r) * K + kc + k4];
            float4 wv = *(const float4*)&W[(size_t)(n0 + r) * K + kc + k4];
            int fo = (r >> 3) * 12 + (r & 7);
            As[k4 + 0][fo] = av.x; As[k4 + 1][fo] = av.y;
            As[k4 + 2][fo] = av.z; As[k4 + 3][fo] = av.w;
            Wt[k4 + 0][fo] = wv.x; Wt[k4 + 1][fo] = wv.y;
            Wt[k4 + 2][fo] = wv.z; Wt[k4 + 3][fo] = wv.w;
        }
        __syncthreads();
        #pragma unroll
        for (int kk = 0; kk < 16; ++kk) {
            float a[8], w[8];
            *(float4*)&a[0] = *(const float4*)&As[kk][am];
            *(float4*)&a[4] = *(const float4*)&As[kk][am + 4];
            *(float4*)&w[0] = *(const float4*)&Wt[kk][wn];
            *(float4*)&w[4] = *(const float4*)&Wt[kk][wn + 4];
            #pragma unroll
            for (int i = 0; i < 8; ++i)
                #pragma unroll
                for (int j = 0; j < 8; ++j)
                    acc[i][j] = fmaf(a[i], w[j], acc[i][j]);
        }
        __syncthreads();
    }
    #pragma unroll
    for (int i = 0; i < 8; ++i) {
        int m = m0 + tm * 8 + i;
        #pragma unroll
        for (int jh = 0; jh < 2; ++jh) {
            float4 v; float* vp = (float*)&v;
            #pragma unroll
            for (int l = 0; l < 4; ++l) {
                int n = n0 + tn * 8 + jh * 4 + l;
                float t = acc[i][jh * 4 + l] + bias[n];
                if (ACT == 1) t = tanhf(t);
                if (ACT == 2) t = fmaxf(t, 0.0f);
                vp[l] = t;
            }
            int nb = n0 + tn * 8 + jh * 4;     // multiple of 4 -> perm keeps f4
            int nc = PERM ? (((nb & 255) >> 2) * 16 + ((nb >> 8) << 2) + (nb & 3)) : nb;
            *(float4*)&C[(size_t)m * N + nc] = v;
        }
    }
}

// ---------------------------------------------------------------------------
// Persistent recurrence kernel. 256 blocks x 256 threads (all co-resident).
// Partition: 4 batch-groups (32 b) x 64 h-groups (4 h dims -> 16 gate rows).
// Recurrent weights live in LDS for all 1024 steps; cx lives in registers.
// Per-step sync: per-batch-group (64 WG) spin barrier, agent scope.
// xg path: gate input projections precomputed (K=256/step).
// fallback:  K=512/step, reloading Wx/Wh slices from L2 each step.
// ---------------------------------------------------------------------------
__global__ __launch_bounds__(256) void recur_kernel(
    float* h_buf,                        // in: h = tanh(fc); out: hs
    const float* __restrict__ xg,        // [TBR][1024] permuted cols, or null
    const float* __restrict__ wx_p,
    const float* __restrict__ wh_p,
    const float* __restrict__ b_p,
    float* hx_buf,                       // [2][128][256]
    int* cnt,                            // [1024][4][16] ints, zeroed
    int use_xg)
{
    __shared__ __align__(16) float Ws[16][260];
    __shared__ __align__(16) float Ss[32][260];
    __shared__ float pres[32][17];
    const int tid = threadIdx.x;
    const int bg = blockIdx.x & 3, hg = blockIdx.x >> 2;
    const int b0 = bg * 32, h0 = hg * 4;
    const int b = tid >> 3, jp = tid & 7;
    const int j0 = jp * 2, j1 = j0 + 1;                     // local rows 0..15
    const int jg0 = (j0 >> 2) * 256 + h0 + (j0 & 3);        // packed row id
    const int jg1 = (j1 >> 2) * 256 + h0 + (j1 & 3);
    const float bias0 = b_p[jg0];
    const float bias1 = b_p[jg1];
    const int wr = tid >> 4;                                // W loader row
    const int wk = (tid & 15) * 16;
    const int wjg = (wr >> 2) * 256 + h0 + (wr & 3);
    const int ob_ = tid >> 2, oh = tid & 3;                 // owner mapping

    if (use_xg) {   // recurrent weights loaded once
        const float* src = wh_p + (size_t)wjg * 256 + wk;
        #pragma unroll
        for (int i = 0; i < 16; i += 4)
            *(float4*)&Ws[wr][wk + i] = *(const float4*)&src[i];
    }

    float cx = 0.0f, hxv = 0.0f;
    long spin_budget = 1L << 27;   // graceful give-up instead of a hang

    for (int t = 0; t < TT; ++t) {
        float acc0 = bias0, acc1 = bias1;
        if (use_xg) {
            const size_t m = (size_t)t * BB + b0 + b;
            acc0 = bias0 * 0.0f + xg[m * 1024 + hg * 16 + j0];  // bias already in xg
            acc1 = xg[m * 1024 + hg * 16 + j1];
        } else {
            // phase A: input contribution with Wx
            {
                const float* srcw = wx_p + (size_t)wjg * 256 + wk;
                #pragma unroll
                for (int i = 0; i < 16; i += 4)
                    *(float4*)&Ws[wr][wk + i] = *(const float4*)&srcw[i];
                const float* srcs = h_buf + ((size_t)t * BB + b0) * HH;
                #pragma unroll
                for (int i = 0; i < 8; ++i) {
                    int fi = tid + 256 * i;
                    float4 v = *(const float4*)&srcs[fi * 4];
                    *(float4*)&Ss[fi >> 6][(fi & 63) * 4] = v;
                }
            }
            __syncthreads();
            #pragma unroll 8
            for (int k = 0; k < 256; k += 4) {
                float4 c4 = *(const float4*)&Ss[b][k];
                float4 wa = *(const float4*)&Ws[j0][k];
                float4 wb = *(const float4*)&Ws[j1][k];
                acc0 += c4.x*wa.x + c4.y*wa.y + c4.z*wa.z + c4.w*wa.w;
                acc1 += c4.x*wb.x + c4.y*wb.y + c4.z*wb.z + c4.w*wb.w;
            }
            __syncthreads();
            {   // reload Wh
                const float* srcw = wh_p + (size_t)wjg * 256 + wk;
                #pragma unroll
                for (int i = 0; i < 16; i += 4)
                    *(float4*)&Ws[wr][wk + i] = *(const float4*)&srcw[i];
            }
        }
        // stage hx slice (contiguous 8192 floats)
        {
            const float* srcs = hx_buf + (size_t)(t & 1) * (BB * HH) + (size_t)b0 * HH;
            #pragma unroll
            for (int i = 0; i < 8; ++i) {
                int fi = tid + 256 * i;
                float4 v = *(const float4*)&srcs[fi * 4];
                *(float4*)&Ss[fi >> 6][(fi & 63) * 4] = v;
            }
        }
        __syncthreads();
        #pragma unroll 8
        for (int k = 0; k < 256; k += 4) {
            float4 c4 = *(const float4*)&Ss[b][k];
            float4 wa = *(const float4*)&Ws[j0][k];
            float4 wb = *(const float4*)&Ws[j1][k];
            acc0 += c4.x*wa.x + c4.y*wa.y + c4.z*wa.z + c4.w*wa.w;
            acc1 += c4.x*wb.x + c4.y*wb.y + c4.z*wb.z + c4.w*wb.w;
        }
        pres[b][j0] = acc0;
        pres[b][j1] = acc1;
        __syncthreads();
        if (tid < 128) {    // gate combine: owner of (b=ob_, h=h0+oh)
            float fg = sigf(pres[ob_][oh]);
            float ig = sigf(pres[ob_][4 + oh]);
            float gg = tanhf(pres[ob_][8 + oh]);
            float og = sigf(pres[ob_][12 + oh]);
            cx = fg * cx + ig * gg;
            hxv = og * tanhf(cx);
            hx_buf[(size_t)((t + 1) & 1) * (BB * HH) + (size_t)(b0 + ob_) * HH + h0 + oh] = hxv;
            __threadfence();
        }
        __syncthreads();
        if (tid == 0) {
            int* c = cnt + ((size_t)t * 4 + bg) * 16;
            __hip_atomic_fetch_add(c, 1, __ATOMIC_ACQ_REL, __HIP_MEMORY_SCOPE_AGENT);
            while (__hip_atomic_load(c, __ATOMIC_RELAXED, __HIP_MEMORY_SCOPE_AGENT) < 64) {
                if (--spin_budget < 0) break;
                __builtin_amdgcn_s_sleep(1);
            }
        }
        __syncthreads();
        __threadfence();     // acquire side: drop stale L1/L2 before next stage
        if (tid < 128)       // publish hs[t] (safe: all peers staged h[t] already)
            h_buf[((size_t)t * BB + b0 + ob_) * HH + h0 + oh] = hxv;
    }
}

// ---------------------------------------------------------------------------
// Final projection: out[m][c] = dot(z1[m], w2[c]) + b2[c], c in {0,1}.
// ---------------------------------------------------------------------------
__global__ __launch_bounds__(256) void final_kernel(
    const float* __restrict__ z, const float* __restrict__ w2,
    const float* __restrict__ b2, float* __restrict__ out)
{
    const int m = blockIdx.x * 128 + (threadIdx.x >> 1);
    const int c = threadIdx.x & 1;
    const float* zr = z + (size_t)m * 256;
    const float* wr = w2 + (size_t)c * 256;
    float s = b2[c];
    #pragma unroll 8
    for (int k = 0; k < 256; k += 4) {
        float4 zv = *(const float4*)&zr[k];
        float4 wv = *(const float4*)&wr[k];
        s += zv.x*wv.x + zv.y*wv.y + zv.z*wv.z + zv.w*wv.w;
    }
    out[(size_t)m * 2 + c] = s;
}

// ---------------------------------------------------------------------------
extern "C" void kernel_launch(void* const* d_in, const int* in_sizes, int n_in,
                              void* d_out, int out_size, void* d_ws, size_t ws_size,
                              hipStream_t stream) {
    const float* x    = (const float*)d_in[0];
    const float* fc_w = (const float*)d_in[1];
    const float* fc_b = (const float*)d_in[2];
    const float* fw   = (const float*)d_in[3];
    const float* fb   = (const float*)d_in[4];
    const float* iw   = (const float*)d_in[5];
    const float* ib   = (const float*)d_in[6];
    const float* uw   = (const float*)d_in[7];
    const float* ub   = (const float*)d_in[8];
    const float* ow   = (const float*)d_in[9];
    const float* ob   = (const float*)d_in[10];
    const float* w0   = (const float*)d_in[11];
    const float* b0   = (const float*)d_in[12];
    const float* w1   = (const float*)d_in[13];
    const float* b1   = (const float*)d_in[14];
    const float* w2   = (const float*)d_in[15];
    const float* b2   = (const float*)d_in[16];
    float* out = (float*)d_out;

    float* ws = (float*)d_ws;
    size_t off = 0;
    float* h_buf  = ws + off; off += (size_t)TBR * HH;     // 33,554,432 f
    float* wx_p   = ws + off; off += 1024 * 256;
    float* wh_p   = ws + off; off += 1024 * 256;
    float* b_p    = ws + off; off += 1024;
    float* hx_buf = ws + off; off += 2 * BB * HH;          // 65,536 f
    int*   cnt    = (int*)(ws + off); off += 65536;        // 65,536 ints
    const size_t base_f = off;
    float* xg = ws + base_f;
    const size_t need_xg = (base_f + (size_t)TBR * 1024) * sizeof(float);
    const int use_xg = (ws_size >= need_xg) ? 1 : 0;
    // z0 scratch: xg region if present, else right after base
    float* z0 = use_xg ? xg : (ws + base_f);

    // zero hx parity buffers + barrier counters (contiguous, 512 KB)
    hipMemsetAsync(hx_buf, 0, (2 * BB * HH + 65536) * sizeof(float), stream);

    pack_kernel<<<1024, 256, 0, stream>>>(fw, iw, uw, ow, fb, ib, ub, ob,
                                          wx_p, wh_p, b_p);
    // FC: h = tanh(x @ fc_w.T + fc_b)
    gemm_kernel<512, 1, 0><<<dim3(TBR / 128, 2), 256, 0, stream>>>(
        x, fc_w, fc_b, h_buf, 256);
    // Gate input projections (bias folded in), permuted col layout
    if (use_xg)
        gemm_kernel<256, 0, 1><<<dim3(TBR / 128, 8), 256, 0, stream>>>(
            h_buf, wx_p, b_p, xg, 1024);
    // Recurrence (persistent)
    recur_kernel<<<256, 256, 0, stream>>>(h_buf, use_xg ? xg : nullptr,
                                          wx_p, wh_p, b_p, hx_buf, cnt, use_xg);
    // Classifier: z0 = relu(hs@W0.T+b0); z1 = relu(z0@W1.T+b1) back into h_buf
    gemm_kernel<256, 2, 0><<<dim3(TBR / 128, 2), 256, 0, stream>>>(
        h_buf, w0, b0, z0, 256);
    gemm_kernel<256, 2, 0><<<dim3(TBR / 128, 2), 256, 0, stream>>>(
        z0, w1, b1, h_buf, 256);
    final_kernel<<<TBR / 128, 256, 0, stream>>>(h_buf, w2, b2, out);
}

// Round 2
// 16788.905 us; speedup vs baseline: 2.3296x; 2.3296x over previous
//
#include <hip/hip_runtime.h>
#include <cstdint>

#define TT 1024
#define BB 128
#define DD 512
#define HH 256
#define TBR (TT*BB)   // 131072 rows

__device__ __forceinline__ float sigf(float x) { return 1.0f / (1.0f + expf(-x)); }

// ---------------------------------------------------------------------------
// Pack gate weights: wx_p[r][k] = W_gate[h][k] (input half), wh_p[r][k] =
// W_gate[h][256+k] (recurrent half), r = gate*256 + h, gates = {f,i,g,o}.
// ---------------------------------------------------------------------------
__global__ __launch_bounds__(256) void pack_kernel(
    const float* __restrict__ fw, const float* __restrict__ iw,
    const float* __restrict__ uw, const float* __restrict__ ow,
    const float* __restrict__ fb, const float* __restrict__ ib,
    const float* __restrict__ ub, const float* __restrict__ obb,
    float* __restrict__ wx_p, float* __restrict__ wh_p, float* __restrict__ b_p)
{
    const int r = blockIdx.x;            // 0..1023
    const int gate = r >> 8, h = r & 255;
    const float* wsrc = gate == 0 ? fw : gate == 1 ? iw : gate == 2 ? uw : ow;
    const float* bsrc = gate == 0 ? fb : gate == 1 ? ib : gate == 2 ? ub : obb;
    const int k = threadIdx.x;           // 0..255
    wx_p[(size_t)r * 256 + k] = wsrc[(size_t)h * 512 + k];
    wh_p[(size_t)r * 256 + k] = wsrc[(size_t)h * 512 + 256 + k];
    if (k == 0) b_p[r] = bsrc[h];
}

// ---------------------------------------------------------------------------
// Generic fp32 GEMM: C[m][n] = act(dot(A[m][:K], W[n][:K]) + bias[n]).
// 128x128 tile, 256 threads, 8x8 register frags.
// PERM=1 permutes output col n -> ((n&255)>>3)*32 + ((n>>8)<<3) + (n&7)
// (the xg layout consumed by recur_kernel: [hg 32][gate 4][h 8]).
// ---------------------------------------------------------------------------
template<int K, int ACT, int PERM>
__global__ __launch_bounds__(256) void gemm_kernel(
    const float* A, const float* __restrict__ W,
    const float* __restrict__ bias, float* C, int N)
{
    __shared__ __align__(16) float As[16][192];
    __shared__ __align__(16) float Wt[16][192];
    const int tid = threadIdx.x;
    const int m0 = blockIdx.x * 128, n0 = blockIdx.y * 128;
    const int tm = tid >> 4, tn = tid & 15;
    const int am = tm * 12, wn = tn * 12;
    float acc[8][8] = {};
    for (int kc = 0; kc < K; kc += 16) {
        #pragma unroll
        for (int i = 0; i < 2; ++i) {
            int f4 = tid + 256 * i;              // 0..511
            int r = f4 >> 2, k4 = (f4 & 3) * 4;
            float4 av = *(const float4*)&A[(size_t)(m0 + r) * K + kc + k4];
            float4 wv = *(const float4*)&W[(size_t)(n0 + r) * K + kc + k4];
            int fo = (r >> 3) * 12 + (r & 7);
            As[k4 + 0][fo] = av.x; As[k4 + 1][fo] = av.y;
            As[k4 + 2][fo] = av.z; As[k4 + 3][fo] = av.w;
            Wt[k4 + 0][fo] = wv.x; Wt[k4 + 1][fo] = wv.y;
            Wt[k4 + 2][fo] = wv.z; Wt[k4 + 3][fo] = wv.w;
        }
        __syncthreads();
        #pragma unroll
        for (int kk = 0; kk < 16; ++kk) {
            float a[8], w[8];
            *(float4*)&a[0] = *(const float4*)&As[kk][am];
            *(float4*)&a[4] = *(const float4*)&As[kk][am + 4];
            *(float4*)&w[0] = *(const float4*)&Wt[kk][wn];
            *(float4*)&w[4] = *(const float4*)&Wt[kk][wn + 4];
            #pragma unroll
            for (int i = 0; i < 8; ++i)
                #pragma unroll
                for (int j = 0; j < 8; ++j)
                    acc[i][j] = fmaf(a[i], w[j], acc[i][j]);
        }
        __syncthreads();
    }
    #pragma unroll
    for (int i = 0; i < 8; ++i) {
        int m = m0 + tm * 8 + i;
        #pragma unroll
        for (int jh = 0; jh < 2; ++jh) {
            float4 v; float* vp = (float*)&v;
            #pragma unroll
            for (int l = 0; l < 4; ++l) {
                int n = n0 + tn * 8 + jh * 4 + l;
                float t = acc[i][jh * 4 + l] + bias[n];
                if (ACT == 1) t = tanhf(t);
                if (ACT == 2) t = fmaxf(t, 0.0f);
                vp[l] = t;
            }
            int nb = n0 + tn * 8 + jh * 4;     // multiple of 4; perm is f4-contiguous
            int nc = PERM ? (((nb & 255) >> 3) * 32 + ((nb >> 8) << 3) + (nb & 7)) : nb;
            *(float4*)&C[(size_t)m * N + nc] = v;
        }
    }
}

// ---------------------------------------------------------------------------
// Persistent recurrence v2. 128 WGs = 4 batch-groups x 32 h-groups; 256 thr.
// Thread (b = tid>>3, h = tid&7) owns cell (b0+b, hg*8+h): computes its own
// 4 gate dots, combines locally, cx in a register.
// Cross-WG exchange: hx ping-pong in global via RELAXED agent atomics
// (sc0/sc1 ops, NO cache-maintenance fences). Barrier: per-(t,bg) flag array
// + ballot poll. Ordering: per-wave s_waitcnt vmcnt(0) before flag store.
// LDS: Ws(weights, resident) + Ss(hx stage), XOR-swizzled, exactly 64 KB.
// ---------------------------------------------------------------------------
__device__ __forceinline__ int swz(int row, int k4) {       // float4 index
    return row * 256 + (((k4 ^ (row & 7)) & 63) << 2);
}

__global__ __launch_bounds__(256, 1) void recur_kernel(
    float* h_buf,                        // in: h = tanh(fc); out: hs
    const float* __restrict__ xg,        // [TBR][1024] permuted cols, or null
    const float* __restrict__ wx_p,
    const float* __restrict__ wh_p,
    const float* __restrict__ b_p,
    float* hx_buf,                       // [2][128][256] ping-pong
    int* flags,                          // [1024][4][32] ints, zeroed
    int use_xg)
{
    __shared__ __align__(16) float Ws[32 * 256];
    __shared__ __align__(16) float Ss[32 * 256];
    const int tid = threadIdx.x;
    const int lane = tid & 63;
    const int bg = blockIdx.x & 3, hg = blockIdx.x >> 2;
    const int b0 = bg * 32;
    const int b = tid >> 3, h = tid & 7;
    const int wrow = tid >> 3;                  // weight loader: row 0..31
    const int wkb = (tid & 7) * 32;             // 32 floats (8 f4) per thread

    // resident recurrent weights (xg path)
    if (use_xg) {
        const int R = (wrow >> 3) * 256 + hg * 8 + (wrow & 7);
        const float* src = wh_p + (size_t)R * 256 + wkb;
        #pragma unroll
        for (int j = 0; j < 8; ++j)
            *(float4*)&Ws[swz(wrow, (wkb >> 2) + j)] = *(const float4*)&src[j * 4];
    }
    float bias0 = 0.f, bias1 = 0.f, bias2 = 0.f, bias3 = 0.f;
    if (!use_xg) {
        bias0 = b_p[0 * 256 + hg * 8 + h];
        bias1 = b_p[1 * 256 + hg * 8 + h];
        bias2 = b_p[2 * 256 + hg * 8 + h];
        bias3 = b_p[3 * 256 + hg * 8 + h];
    }
    __syncthreads();

    float cx = 0.0f, pv = 0.0f;

    for (int t = 0; t < TT; ++t) {
        // prefetch xg for this step (independent of the barrier)
        float xq0, xq1, xq2, xq3;
        if (use_xg) {
            const float* xr = xg + ((size_t)t * BB + b0 + b) * 1024 + hg * 32 + h;
            xq0 = xr[0]; xq1 = xr[8]; xq2 = xr[16]; xq3 = xr[24];
        }
        // wait for all 32 h-group peers of this bg to finish step t-1
        if (t > 0) {
            const int* fp = flags + (size_t)(t - 1) * 128 + bg * 32 + (lane & 31);
            long bud = 1L << 22;
            for (;;) {
                int v = __hip_atomic_load(fp, __ATOMIC_RELAXED, __HIP_MEMORY_SCOPE_AGENT);
                if (__all(v != 0)) break;
                if (--bud < 0) break;
                __builtin_amdgcn_s_sleep(1);
            }
        }

        float acc0, acc1, acc2, acc3;
        if (use_xg) {
            acc0 = xq0; acc1 = xq1; acc2 = xq2; acc3 = xq3;   // bias folded in
        } else {
            // ---- fallback: delayed hs publish for t-1 (peers all staged h[t-1])
            if (t > 0)
                h_buf[((size_t)(t - 1) * BB + b0 + b) * 256 + hg * 8 + h] = pv;
            acc0 = bias0; acc1 = bias1; acc2 = bias2; acc3 = bias3;
            // load Wx slice + stage h_t, dot phase A
            {
                const int R = (wrow >> 3) * 256 + hg * 8 + (wrow & 7);
                const float* src = wx_p + (size_t)R * 256 + wkb;
                #pragma unroll
                for (int j = 0; j < 8; ++j)
                    *(float4*)&Ws[swz(wrow, (wkb >> 2) + j)] = *(const float4*)&src[j * 4];
                const float* hs = h_buf + ((size_t)t * BB + b0) * HH;
                #pragma unroll
                for (int i = 0; i < 32; ++i)
                    Ss[i * 256 + ((((tid >> 2) ^ (i & 7)) & 63) << 2) + (tid & 3)] =
                        hs[i * 256 + tid];
            }
            __syncthreads();
            #pragma unroll 4
            for (int k4 = 0; k4 < 64; ++k4) {
                float4 s  = *(const float4*)&Ss[swz(b, k4)];
                float4 w0 = *(const float4*)&Ws[(0 * 8 + h) * 256 + (((k4 ^ h) & 63) << 2)];
                float4 w1 = *(const float4*)&Ws[(1 * 8 + h) * 256 + (((k4 ^ h) & 63) << 2)];
                float4 w2 = *(const float4*)&Ws[(2 * 8 + h) * 256 + (((k4 ^ h) & 63) << 2)];
                float4 w3 = *(const float4*)&Ws[(3 * 8 + h) * 256 + (((k4 ^ h) & 63) << 2)];
                acc0 += s.x*w0.x + s.y*w0.y + s.z*w0.z + s.w*w0.w;
                acc1 += s.x*w1.x + s.y*w1.y + s.z*w1.z + s.w*w1.w;
                acc2 += s.x*w2.x + s.y*w2.y + s.z*w2.z + s.w*w2.w;
                acc3 += s.x*w3.x + s.y*w3.y + s.z*w3.z + s.w*w3.w;
            }
            __syncthreads();
            {   // reload Wh
                const int R = (wrow >> 3) * 256 + hg * 8 + (wrow & 7);
                const float* src = wh_p + (size_t)R * 256 + wkb;
                #pragma unroll
                for (int j = 0; j < 8; ++j)
                    *(float4*)&Ws[swz(wrow, (wkb >> 2) + j)] = *(const float4*)&src[j * 4];
            }
        }

        // stage hx (step-t state) from the ping-pong buffer: coherent loads
        {
            const float* hxr = hx_buf + (size_t)(t & 1) * (BB * HH) + (size_t)b0 * HH;
            #pragma unroll
            for (int i = 0; i < 32; ++i) {
                float v = __hip_atomic_load(&hxr[i * 256 + tid],
                                            __ATOMIC_RELAXED, __HIP_MEMORY_SCOPE_AGENT);
                Ss[i * 256 + ((((tid >> 2) ^ (i & 7)) & 63) << 2) + (tid & 3)] = v;
            }
        }
        __syncthreads();
        #pragma unroll 4
        for (int k4 = 0; k4 < 64; ++k4) {
            float4 s  = *(const float4*)&Ss[swz(b, k4)];
            float4 w0 = *(const float4*)&Ws[(0 * 8 + h) * 256 + (((k4 ^ h) & 63) << 2)];
            float4 w1 = *(const float4*)&Ws[(1 * 8 + h) * 256 + (((k4 ^ h) & 63) << 2)];
            float4 w2 = *(const float4*)&Ws[(2 * 8 + h) * 256 + (((k4 ^ h) & 63) << 2)];
            float4 w3 = *(const float4*)&Ws[(3 * 8 + h) * 256 + (((k4 ^ h) & 63) << 2)];
            acc0 += s.x*w0.x + s.y*w0.y + s.z*w0.z + s.w*w0.w;
            acc1 += s.x*w1.x + s.y*w1.y + s.z*w1.z + s.w*w1.w;
            acc2 += s.x*w2.x + s.y*w2.y + s.z*w2.z + s.w*w2.w;
            acc3 += s.x*w3.x + s.y*w3.y + s.z*w3.z + s.w*w3.w;
        }
        __syncthreads();   // Ss free for next step's staging

        // local gate combine (f,i,g,o)
        float fg = sigf(acc0), ig = sigf(acc1), gg = tanhf(acc2), og = sigf(acc3);
        cx = fg * cx + ig * gg;
        float hxv = og * tanhf(cx);
        pv = hxv;

        // publish hx cell for step t+1: coherent store
        __hip_atomic_store(
            &hx_buf[(size_t)((t + 1) & 1) * (BB * HH) + (size_t)(b0 + b) * HH + hg * 8 + h],
            hxv, __ATOMIC_RELAXED, __HIP_MEMORY_SCOPE_AGENT);
        asm volatile("s_waitcnt vmcnt(0)" ::: "memory");   // drain this wave's stores
        __syncthreads();                                   // all waves drained
        if (tid == 0)
            __hip_atomic_store(&flags[(size_t)t * 128 + bg * 32 + hg], 1,
                               __ATOMIC_RELAXED, __HIP_MEMORY_SCOPE_AGENT);
        if (use_xg)   // hs output (not read cross-WG in xg mode)
            h_buf[((size_t)t * BB + b0 + b) * 256 + hg * 8 + h] = hxv;
    }

    if (!use_xg) {   // publish last hs after everyone staged h[1023]
        const int* fp = flags + (size_t)1023 * 128 + bg * 32 + (lane & 31);
        long bud = 1L << 22;
        for (;;) {
            int v = __hip_atomic_load(fp, __ATOMIC_RELAXED, __HIP_MEMORY_SCOPE_AGENT);
            if (__all(v != 0)) break;
            if (--bud < 0) break;
            __builtin_amdgcn_s_sleep(1);
        }
        h_buf[((size_t)1023 * BB + b0 + b) * 256 + hg * 8 + h] = pv;
    }
}

// ---------------------------------------------------------------------------
// Final projection: out[m][c] = dot(z1[m], w2[c]) + b2[c], c in {0,1}.
// ---------------------------------------------------------------------------
__global__ __launch_bounds__(256) void final_kernel(
    const float* __restrict__ z, const float* __restrict__ w2,
    const float* __restrict__ b2, float* __restrict__ out)
{
    const int m = blockIdx.x * 128 + (threadIdx.x >> 1);
    const int c = threadIdx.x & 1;
    const float* zr = z + (size_t)m * 256;
    const float* wr = w2 + (size_t)c * 256;
    float s = b2[c];
    #pragma unroll 8
    for (int k = 0; k < 256; k += 4) {
        float4 zv = *(const float4*)&zr[k];
        float4 wv = *(const float4*)&wr[k];
        s += zv.x*wv.x + zv.y*wv.y + zv.z*wv.z + zv.w*wv.w;
    }
    out[(size_t)m * 2 + c] = s;
}

// ---------------------------------------------------------------------------
extern "C" void kernel_launch(void* const* d_in, const int* in_sizes, int n_in,
                              void* d_out, int out_size, void* d_ws, size_t ws_size,
                              hipStream_t stream) {
    const float* x    = (const float*)d_in[0];
    const float* fc_w = (const float*)d_in[1];
    const float* fc_b = (const float*)d_in[2];
    const float* fw   = (const float*)d_in[3];
    const float* fb   = (const float*)d_in[4];
    const float* iw   = (const float*)d_in[5];
    const float* ib   = (const float*)d_in[6];
    const float* uw   = (const float*)d_in[7];
    const float* ub   = (const float*)d_in[8];
    const float* ow   = (const float*)d_in[9];
    const float* ob   = (const float*)d_in[10];
    const float* w0   = (const float*)d_in[11];
    const float* b0   = (const float*)d_in[12];
    const float* w1   = (const float*)d_in[13];
    const float* b1   = (const float*)d_in[14];
    const float* w2   = (const float*)d_in[15];
    const float* b2   = (const float*)d_in[16];
    float* out = (float*)d_out;

    float* ws = (float*)d_ws;
    size_t off = 0;
    float* h_buf  = ws + off; off += (size_t)TBR * HH;     // 33,554,432 f
    float* wx_p   = ws + off; off += 1024 * 256;
    float* wh_p   = ws + off; off += 1024 * 256;
    float* b_p    = ws + off; off += 1024;
    float* hx_buf = ws + off; off += 2 * BB * HH;          // 65,536 f
    int*   flags  = (int*)(ws + off); off += 131072;       // 1024*4*32 ints
    const size_t base_f = off;
    float* xg = ws + base_f;
    const size_t need_xg = (base_f + (size_t)TBR * 1024) * sizeof(float);
    const int use_xg = (ws_size >= need_xg) ? 1 : 0;
    float* z0 = use_xg ? xg : (ws + base_f);

    // zero hx ping-pong + flags (contiguous, 768 KB)
    hipMemsetAsync(hx_buf, 0, (2 * BB * HH + 131072) * sizeof(float), stream);

    pack_kernel<<<1024, 256, 0, stream>>>(fw, iw, uw, ow, fb, ib, ub, ob,
                                          wx_p, wh_p, b_p);
    // FC: h = tanh(x @ fc_w.T + fc_b)
    gemm_kernel<512, 1, 0><<<dim3(TBR / 128, 2), 256, 0, stream>>>(
        x, fc_w, fc_b, h_buf, 256);
    // Gate input projections (bias folded in), permuted col layout
    if (use_xg)
        gemm_kernel<256, 0, 1><<<dim3(TBR / 128, 8), 256, 0, stream>>>(
            h_buf, wx_p, b_p, xg, 1024);
    // Recurrence (persistent, 128 WGs co-resident)
    recur_kernel<<<128, 256, 0, stream>>>(h_buf, use_xg ? xg : nullptr,
                                          wx_p, wh_p, b_p, hx_buf, flags, use_xg);
    // Classifier: z0 = relu(hs@W0.T+b0); z1 = relu(z0@W1.T+b1) back into h_buf
    gemm_kernel<256, 2, 0><<<dim3(TBR / 128, 2), 256, 0, stream>>>(
        h_buf, w0, b0, z0, 256);
    gemm_kernel<256, 2, 0><<<dim3(TBR / 128, 2), 256, 0, stream>>>(
        z0, w1, b1, h_buf, 256);
    final_kernel<<<TBR / 128, 256, 0, stream>>>(h_buf, w2, b2, out);
}

// Round 3
// 4998.367 us; speedup vs baseline: 7.8249x; 3.3589x over previous
//
#include <hip/hip_runtime.h>
#include <cstdint>

#define TT 1024
#define BB 128
#define DD 512
#define HH 256
#define TBR (TT*BB)   // 131072 rows

typedef __attribute__((ext_vector_type(8))) short  s8v;     // 8 bf16 (4 VGPR)
typedef __attribute__((ext_vector_type(4))) float  f4v;     // MFMA acc
typedef __attribute__((ext_vector_type(4))) unsigned u4v;

__device__ __forceinline__ float sigf(float x) { return 1.0f / (1.0f + expf(-x)); }

__device__ __forceinline__ unsigned rnbf(float f) {         // fp32 -> bf16 bits (RN)
    unsigned u = __builtin_bit_cast(unsigned, f);
    return (u + 0x7FFFu + ((u >> 16) & 1u)) >> 16;
}

// ---------------------------------------------------------------------------
// Old packing (fallback path): r = gate*256 + h.
// ---------------------------------------------------------------------------
__global__ __launch_bounds__(256) void pack_kernel(
    const float* __restrict__ fw, const float* __restrict__ iw,
    const float* __restrict__ uw, const float* __restrict__ ow,
    const float* __restrict__ fb, const float* __restrict__ ib,
    const float* __restrict__ ub, const float* __restrict__ obb,
    float* __restrict__ wx_p, float* __restrict__ wh_p, float* __restrict__ b_p)
{
    const int r = blockIdx.x;
    const int gate = r >> 8, h = r & 255;
    const float* wsrc = gate == 0 ? fw : gate == 1 ? iw : gate == 2 ? uw : ow;
    const float* bsrc = gate == 0 ? fb : gate == 1 ? ib : gate == 2 ? ub : obb;
    const int k = threadIdx.x;
    wx_p[(size_t)r * 256 + k] = wsrc[(size_t)h * 512 + k];
    wh_p[(size_t)r * 256 + k] = wsrc[(size_t)h * 512 + 256 + k];
    if (k == 0) b_p[r] = bsrc[h];
}

// ---------------------------------------------------------------------------
// MFMA packing: r = hg*128 + g*32 + hrem, h = hg*32 + hrem  (hg=0..7).
// Each 128-row block = all 4 gates for one 32-wide h slice -> one WG.
// ---------------------------------------------------------------------------
__global__ __launch_bounds__(256) void pack_mfma(
    const float* __restrict__ fw, const float* __restrict__ iw,
    const float* __restrict__ uw, const float* __restrict__ ow,
    const float* __restrict__ fb, const float* __restrict__ ib,
    const float* __restrict__ ub, const float* __restrict__ obb,
    float* __restrict__ wx_p, float* __restrict__ wh_p, float* __restrict__ b_p)
{
    const int r = blockIdx.x;                 // 0..1023
    const int gate = (r >> 5) & 3;
    const int h = (r >> 7) * 32 + (r & 31);
    const float* wsrc = gate == 0 ? fw : gate == 1 ? iw : gate == 2 ? uw : ow;
    const float* bsrc = gate == 0 ? fb : gate == 1 ? ib : gate == 2 ? ub : obb;
    const int k = threadIdx.x;
    wx_p[(size_t)r * 256 + k] = wsrc[(size_t)h * 512 + k];
    wh_p[(size_t)r * 256 + k] = wsrc[(size_t)h * 512 + 256 + k];
    if (k == 0) b_p[r] = bsrc[h];
}

// ---------------------------------------------------------------------------
// fp32 GEMM: C[m][n] = act(dot(A[m][:K], W[n][:K]) + bias[n]). 128x128 tile.
// PERM=1: old xg layout (fallback only).
// ---------------------------------------------------------------------------
template<int K, int ACT, int PERM>
__global__ __launch_bounds__(256) void gemm_kernel(
    const float* A, const float* __restrict__ W,
    const float* __restrict__ bias, float* C, int N)
{
    __shared__ __align__(16) float As[16][192];
    __shared__ __align__(16) float Wt[16][192];
    const int tid = threadIdx.x;
    const int m0 = blockIdx.x * 128, n0 = blockIdx.y * 128;
    const int tm = tid >> 4, tn = tid & 15;
    const int am = tm * 12, wn = tn * 12;
    float acc[8][8] = {};
    for (int kc = 0; kc < K; kc += 16) {
        #pragma unroll
        for (int i = 0; i < 2; ++i) {
            int f4 = tid + 256 * i;
            int r = f4 >> 2, k4 = (f4 & 3) * 4;
            float4 av = *(const float4*)&A[(size_t)(m0 + r) * K + kc + k4];
            float4 wv = *(const float4*)&W[(size_t)(n0 + r) * K + kc + k4];
            int fo = (r >> 3) * 12 + (r & 7);
            As[k4 + 0][fo] = av.x; As[k4 + 1][fo] = av.y;
            As[k4 + 2][fo] = av.z; As[k4 + 3][fo] = av.w;
            Wt[k4 + 0][fo] = wv.x; Wt[k4 + 1][fo] = wv.y;
            Wt[k4 + 2][fo] = wv.z; Wt[k4 + 3][fo] = wv.w;
        }
        __syncthreads();
        #pragma unroll
        for (int kk = 0; kk < 16; ++kk) {
            float a[8], w[8];
            *(float4*)&a[0] = *(const float4*)&As[kk][am];
            *(float4*)&a[4] = *(const float4*)&As[kk][am + 4];
            *(float4*)&w[0] = *(const float4*)&Wt[kk][wn];
            *(float4*)&w[4] = *(const float4*)&Wt[kk][wn + 4];
            #pragma unroll
            for (int i = 0; i < 8; ++i)
                #pragma unroll
                for (int j = 0; j < 8; ++j)
                    acc[i][j] = fmaf(a[i], w[j], acc[i][j]);
        }
        __syncthreads();
    }
    #pragma unroll
    for (int i = 0; i < 8; ++i) {
        int m = m0 + tm * 8 + i;
        #pragma unroll
        for (int jh = 0; jh < 2; ++jh) {
            float4 v; float* vp = (float*)&v;
            #pragma unroll
            for (int l = 0; l < 4; ++l) {
                int n = n0 + tn * 8 + jh * 4 + l;
                float t = acc[i][jh * 4 + l] + bias[n];
                if (ACT == 1) t = tanhf(t);
                if (ACT == 2) t = fmaxf(t, 0.0f);
                vp[l] = t;
            }
            int nb = n0 + tn * 8 + jh * 4;
            int nc = PERM ? (((nb & 255) >> 3) * 32 + ((nb >> 8) << 3) + (nb & 7)) : nb;
            *(float4*)&C[(size_t)m * N + nc] = v;
        }
    }
}

// ---------------------------------------------------------------------------
// MFMA recurrence. 64 WGs = 8 bg(16 batches) x 8 hg(128 packed gate rows).
// Wh resident in VGPRs as split-bf16 (hi+lo) B-fragments (128 VGPR/wave).
// Per step: stage hx (hi|lo packed dwords, relaxed agent atomics) -> LDS,
// 48 MFMAs/wave (2 ntiles x 8 ks x 3 split terms), C->LDS exchange, local
// gate combine (cx in regs), publish hx + per-(bg,hg) flag; poll 8 peers.
// ---------------------------------------------------------------------------
__global__ __launch_bounds__(256, 1) void recur_mfma(
    float* __restrict__ h_buf,            // in: tanh(fc) [unused]; out: hs
    const float* __restrict__ xg,         // [TBR][1024] packed cols, fp32
    const float* __restrict__ wh_mf,      // [1024][256] packed
    unsigned* hxh, unsigned* hxl,         // [2][128][128] dwords (2 bf16 each)
    int* flags)                           // [1024][8][8], zeroed
{
    __shared__ __align__(16) unsigned ldsH[16 * 128];
    __shared__ __align__(16) unsigned ldsL[16 * 128];
    __shared__ float pre[16][132];
    const int tid = threadIdx.x;
    const int lane = tid & 63;
    const int wv = tid >> 6;
    const int bg = blockIdx.x & 7, hg = blockIdx.x >> 3;
    const int b0 = bg * 16;
    const int nlo = lane & 15, quad = lane >> 4;

    // ---- one-time: Wh -> registers as split-bf16 B-fragments
    s8v bh[2][8], bl[2][8];
    #pragma unroll
    for (int nt = 0; nt < 2; ++nt) {
        int r = hg * 128 + wv * 32 + nt * 16 + nlo;
        #pragma unroll
        for (int ks = 0; ks < 8; ++ks) {
            const float* src = wh_mf + (size_t)r * 256 + ks * 32 + quad * 8;
            u4v uh, ul;
            #pragma unroll
            for (int p = 0; p < 4; ++p) {
                float f0 = src[2 * p], f1 = src[2 * p + 1];
                unsigned h0 = rnbf(f0), h1 = rnbf(f1);
                float r0 = f0 - __builtin_bit_cast(float, h0 << 16);
                float r1 = f1 - __builtin_bit_cast(float, h1 << 16);
                uh[p] = h0 | (rnbf(0.0f), h1 << 16);
                uh[p] = h0 | (h1 << 16);
                ul[p] = rnbf(r0) | (rnbf(r1) << 16);
            }
            bh[nt][ks] = __builtin_bit_cast(s8v, uh);
            bl[nt][ks] = __builtin_bit_cast(s8v, ul);
        }
    }

    const int sm = tid >> 4;             // staging row 0..15
    const int sc0 = (tid & 15) * 2;      // first of 2 chunks (16B) per thread
    const int cb = tid >> 4, q = tid & 15;  // combine: batch row, h-pair

    float cx0 = 0.0f, cx1 = 0.0f;

    for (int t = 0; t < TT; ++t) {
        // prefetch xg for this step (plain loads; no flag dependency)
        float2 xq[4];
        {
            const float* xr = xg + ((size_t)t * BB + b0 + cb) * 1024 + hg * 128 + 2 * q;
            #pragma unroll
            for (int g = 0; g < 4; ++g)
                xq[g] = *(const float2*)&xr[g * 32];
        }
        // wait for the 8 h-group peers of this bg to finish step t-1
        if (t > 0) {
            const int* fp = flags + ((size_t)(t - 1) * 8 + bg) * 8 + (lane & 7);
            long bud = 1L << 22;
            for (;;) {
                int v = __hip_atomic_load(fp, __ATOMIC_RELAXED, __HIP_MEMORY_SCOPE_AGENT);
                if (__all(v != 0)) break;
                if (--bud < 0) break;
                __builtin_amdgcn_s_sleep(1);
            }
        }
        // stage hx parity (t&1): 16 rows x 128 dwords, hi/lo planes, swizzled
        {
            const size_t rowd = ((size_t)(t & 1) * 128 + b0 + sm) * 128 + sc0 * 4;
            const unsigned long long* gh = (const unsigned long long*)(hxh + rowd);
            const unsigned long long* gl = (const unsigned long long*)(hxl + rowd);
            unsigned long long a0 = __hip_atomic_load(gh + 0, __ATOMIC_RELAXED, __HIP_MEMORY_SCOPE_AGENT);
            unsigned long long a1 = __hip_atomic_load(gh + 1, __ATOMIC_RELAXED, __HIP_MEMORY_SCOPE_AGENT);
            unsigned long long a2 = __hip_atomic_load(gh + 2, __ATOMIC_RELAXED, __HIP_MEMORY_SCOPE_AGENT);
            unsigned long long a3 = __hip_atomic_load(gh + 3, __ATOMIC_RELAXED, __HIP_MEMORY_SCOPE_AGENT);
            unsigned long long c0 = __hip_atomic_load(gl + 0, __ATOMIC_RELAXED, __HIP_MEMORY_SCOPE_AGENT);
            unsigned long long c1 = __hip_atomic_load(gl + 1, __ATOMIC_RELAXED, __HIP_MEMORY_SCOPE_AGENT);
            unsigned long long c2 = __hip_atomic_load(gl + 2, __ATOMIC_RELAXED, __HIP_MEMORY_SCOPE_AGENT);
            unsigned long long c3 = __hip_atomic_load(gl + 3, __ATOMIC_RELAXED, __HIP_MEMORY_SCOPE_AGENT);
            int p0 = sm * 128 + ((sc0 ^ (sm & 7)) << 2);
            int p1 = sm * 128 + (((sc0 + 1) ^ (sm & 7)) << 2);
            u4v w0 = { (unsigned)a0, (unsigned)(a0 >> 32), (unsigned)a1, (unsigned)(a1 >> 32) };
            u4v w1 = { (unsigned)a2, (unsigned)(a2 >> 32), (unsigned)a3, (unsigned)(a3 >> 32) };
            u4v v0 = { (unsigned)c0, (unsigned)(c0 >> 32), (unsigned)c1, (unsigned)(c1 >> 32) };
            u4v v1 = { (unsigned)c2, (unsigned)(c2 >> 32), (unsigned)c3, (unsigned)(c3 >> 32) };
            *(u4v*)&ldsH[p0] = w0; *(u4v*)&ldsH[p1] = w1;
            *(u4v*)&ldsL[p0] = v0; *(u4v*)&ldsL[p1] = v1;
        }
        __syncthreads();

        // MFMA: acc[nt] = sum_k (Whi*xhi + Whi*xlo + Wlo*xhi)
        f4v acc0 = {0.f, 0.f, 0.f, 0.f}, acc1 = {0.f, 0.f, 0.f, 0.f};
        #pragma unroll
        for (int ks = 0; ks < 8; ++ks) {
            int off = nlo * 128 + ((((ks * 4 + quad) ^ (nlo & 7))) << 2);
            s8v ah = __builtin_bit_cast(s8v, *(const u4v*)&ldsH[off]);
            s8v al = __builtin_bit_cast(s8v, *(const u4v*)&ldsL[off]);
            acc0 = __builtin_amdgcn_mfma_f32_16x16x32_bf16(ah, bh[0][ks], acc0, 0, 0, 0);
            acc1 = __builtin_amdgcn_mfma_f32_16x16x32_bf16(ah, bh[1][ks], acc1, 0, 0, 0);
            acc0 = __builtin_amdgcn_mfma_f32_16x16x32_bf16(al, bh[0][ks], acc0, 0, 0, 0);
            acc1 = __builtin_amdgcn_mfma_f32_16x16x32_bf16(al, bh[1][ks], acc1, 0, 0, 0);
            acc0 = __builtin_amdgcn_mfma_f32_16x16x32_bf16(ah, bl[0][ks], acc0, 0, 0, 0);
            acc1 = __builtin_amdgcn_mfma_f32_16x16x32_bf16(ah, bl[1][ks], acc1, 0, 0, 0);
        }
        // C-frags -> pre[m][n]: row m = quad*4+reg, col n = lane&15 (+tile base)
        {
            int n0c = wv * 32 + nlo;
            #pragma unroll
            for (int reg = 0; reg < 4; ++reg) {
                pre[quad * 4 + reg][n0c]      = acc0[reg];
                pre[quad * 4 + reg][n0c + 16] = acc1[reg];
            }
        }
        __syncthreads();

        // local gate combine: thread owns cells (b0+cb, hg*32+2q / +1)
        float2 pf = *(const float2*)&pre[cb][0 * 32 + 2 * q];
        float2 pi = *(const float2*)&pre[cb][1 * 32 + 2 * q];
        float2 pg = *(const float2*)&pre[cb][2 * 32 + 2 * q];
        float2 po = *(const float2*)&pre[cb][3 * 32 + 2 * q];
        float f0 = sigf(pf.x + xq[0].x), f1 = sigf(pf.y + xq[0].y);
        float i0 = sigf(pi.x + xq[1].x), i1 = sigf(pi.y + xq[1].y);
        float g0 = tanhf(pg.x + xq[2].x), g1 = tanhf(pg.y + xq[2].y);
        float o0 = sigf(po.x + xq[3].x), o1 = sigf(po.y + xq[3].y);
        cx0 = f0 * cx0 + i0 * g0;
        cx1 = f1 * cx1 + i1 * g1;
        float hv0 = o0 * tanhf(cx0);
        float hv1 = o1 * tanhf(cx1);

        // publish: hx (split-bf16 packed dwords) + hs (fp32)
        unsigned hb0 = rnbf(hv0), hb1 = rnbf(hv1);
        float l0 = hv0 - __builtin_bit_cast(float, hb0 << 16);
        float l1 = hv1 - __builtin_bit_cast(float, hb1 << 16);
        const size_t oc = ((size_t)((t + 1) & 1) * 128 + b0 + cb) * 128 + hg * 16 + q;
        __hip_atomic_store(&hxh[oc], hb0 | (hb1 << 16),
                           __ATOMIC_RELAXED, __HIP_MEMORY_SCOPE_AGENT);
        __hip_atomic_store(&hxl[oc], rnbf(l0) | (rnbf(l1) << 16),
                           __ATOMIC_RELAXED, __HIP_MEMORY_SCOPE_AGENT);
        *(float2*)&h_buf[((size_t)t * BB + b0 + cb) * 256 + hg * 32 + 2 * q] =
            make_float2(hv0, hv1);
        asm volatile("s_waitcnt vmcnt(0)" ::: "memory");   // drain this wave
        __syncthreads();                                   // all waves drained
        if (tid == 0)
            __hip_atomic_store(&flags[((size_t)t * 8 + bg) * 8 + hg], 1,
                               __ATOMIC_RELAXED, __HIP_MEMORY_SCOPE_AGENT);
    }
}

// ---------------------------------------------------------------------------
// Fallback scalar recurrence (round-2 kernel, old packing), used if ws too
// small for xg. Unchanged.
// ---------------------------------------------------------------------------
__device__ __forceinline__ int swz(int row, int k4) {
    return row * 256 + (((k4 ^ (row & 7)) & 63) << 2);
}

__global__ __launch_bounds__(256, 1) void recur_kernel(
    float* h_buf, const float* __restrict__ xg,
    const float* __restrict__ wx_p, const float* __restrict__ wh_p,
    const float* __restrict__ b_p, float* hx_buf, int* flags, int use_xg)
{
    __shared__ __align__(16) float Ws[32 * 256];
    __shared__ __align__(16) float Ss[32 * 256];
    const int tid = threadIdx.x;
    const int lane = tid & 63;
    const int bg = blockIdx.x & 3, hg = blockIdx.x >> 2;
    const int b0 = bg * 32;
    const int b = tid >> 3, h = tid & 7;
    const int wrow = tid >> 3;
    const int wkb = (tid & 7) * 32;

    float bias0 = b_p[0 * 256 + hg * 8 + h];
    float bias1 = b_p[1 * 256 + hg * 8 + h];
    float bias2 = b_p[2 * 256 + hg * 8 + h];
    float bias3 = b_p[3 * 256 + hg * 8 + h];
    __syncthreads();

    float cx = 0.0f, pv = 0.0f;

    for (int t = 0; t < TT; ++t) {
        if (t > 0) {
            const int* fp = flags + (size_t)(t - 1) * 128 + bg * 32 + (lane & 31);
            long bud = 1L << 22;
            for (;;) {
                int v = __hip_atomic_load(fp, __ATOMIC_RELAXED, __HIP_MEMORY_SCOPE_AGENT);
                if (__all(v != 0)) break;
                if (--bud < 0) break;
                __builtin_amdgcn_s_sleep(1);
            }
        }
        float acc0, acc1, acc2, acc3;
        {
            if (t > 0)
                h_buf[((size_t)(t - 1) * BB + b0 + b) * 256 + hg * 8 + h] = pv;
            acc0 = bias0; acc1 = bias1; acc2 = bias2; acc3 = bias3;
            {
                const int R = (wrow >> 3) * 256 + hg * 8 + (wrow & 7);
                const float* src = wx_p + (size_t)R * 256 + wkb;
                #pragma unroll
                for (int j = 0; j < 8; ++j)
                    *(float4*)&Ws[swz(wrow, (wkb >> 2) + j)] = *(const float4*)&src[j * 4];
                const float* hs = h_buf + ((size_t)t * BB + b0) * HH;
                #pragma unroll
                for (int i = 0; i < 32; ++i)
                    Ss[i * 256 + ((((tid >> 2) ^ (i & 7)) & 63) << 2) + (tid & 3)] =
                        hs[i * 256 + tid];
            }
            __syncthreads();
            #pragma unroll 4
            for (int k4 = 0; k4 < 64; ++k4) {
                float4 s  = *(const float4*)&Ss[swz(b, k4)];
                float4 w0 = *(const float4*)&Ws[(0 * 8 + h) * 256 + (((k4 ^ h) & 63) << 2)];
                float4 w1 = *(const float4*)&Ws[(1 * 8 + h) * 256 + (((k4 ^ h) & 63) << 2)];
                float4 w2 = *(const float4*)&Ws[(2 * 8 + h) * 256 + (((k4 ^ h) & 63) << 2)];
                float4 w3 = *(const float4*)&Ws[(3 * 8 + h) * 256 + (((k4 ^ h) & 63) << 2)];
                acc0 += s.x*w0.x + s.y*w0.y + s.z*w0.z + s.w*w0.w;
                acc1 += s.x*w1.x + s.y*w1.y + s.z*w1.z + s.w*w1.w;
                acc2 += s.x*w2.x + s.y*w2.y + s.z*w2.z + s.w*w2.w;
                acc3 += s.x*w3.x + s.y*w3.y + s.z*w3.z + s.w*w3.w;
            }
            __syncthreads();
            {
                const int R = (wrow >> 3) * 256 + hg * 8 + (wrow & 7);
                const float* src = wh_p + (size_t)R * 256 + wkb;
                #pragma unroll
                for (int j = 0; j < 8; ++j)
                    *(float4*)&Ws[swz(wrow, (wkb >> 2) + j)] = *(const float4*)&src[j * 4];
            }
        }
        {
            const float* hxr = hx_buf + (size_t)(t & 1) * (BB * HH) + (size_t)b0 * HH;
            #pragma unroll
            for (int i = 0; i < 32; ++i) {
                float v = __hip_atomic_load(&hxr[i * 256 + tid],
                                            __ATOMIC_RELAXED, __HIP_MEMORY_SCOPE_AGENT);
                Ss[i * 256 + ((((tid >> 2) ^ (i & 7)) & 63) << 2) + (tid & 3)] = v;
            }
        }
        __syncthreads();
        #pragma unroll 4
        for (int k4 = 0; k4 < 64; ++k4) {
            float4 s  = *(const float4*)&Ss[swz(b, k4)];
            float4 w0 = *(const float4*)&Ws[(0 * 8 + h) * 256 + (((k4 ^ h) & 63) << 2)];
            float4 w1 = *(const float4*)&Ws[(1 * 8 + h) * 256 + (((k4 ^ h) & 63) << 2)];
            float4 w2 = *(const float4*)&Ws[(2 * 8 + h) * 256 + (((k4 ^ h) & 63) << 2)];
            float4 w3 = *(const float4*)&Ws[(3 * 8 + h) * 256 + (((k4 ^ h) & 63) << 2)];
            acc0 += s.x*w0.x + s.y*w0.y + s.z*w0.z + s.w*w0.w;
            acc1 += s.x*w1.x + s.y*w1.y + s.z*w1.z + s.w*w1.w;
            acc2 += s.x*w2.x + s.y*w2.y + s.z*w2.z + s.w*w2.w;
            acc3 += s.x*w3.x + s.y*w3.y + s.z*w3.z + s.w*w3.w;
        }
        __syncthreads();

        float fg = sigf(acc0), ig = sigf(acc1), gg = tanhf(acc2), og = sigf(acc3);
        cx = fg * cx + ig * gg;
        float hxv = og * tanhf(cx);
        pv = hxv;

        __hip_atomic_store(
            &hx_buf[(size_t)((t + 1) & 1) * (BB * HH) + (size_t)(b0 + b) * HH + hg * 8 + h],
            hxv, __ATOMIC_RELAXED, __HIP_MEMORY_SCOPE_AGENT);
        asm volatile("s_waitcnt vmcnt(0)" ::: "memory");
        __syncthreads();
        if (tid == 0)
            __hip_atomic_store(&flags[(size_t)t * 128 + bg * 32 + hg], 1,
                               __ATOMIC_RELAXED, __HIP_MEMORY_SCOPE_AGENT);
    }

    {
        const int* fp = flags + (size_t)1023 * 128 + bg * 32 + (lane & 31);
        long bud = 1L << 22;
        for (;;) {
            int v = __hip_atomic_load(fp, __ATOMIC_RELAXED, __HIP_MEMORY_SCOPE_AGENT);
            if (__all(v != 0)) break;
            if (--bud < 0) break;
            __builtin_amdgcn_s_sleep(1);
        }
        h_buf[((size_t)1023 * BB + b0 + b) * 256 + hg * 8 + h] = pv;
    }
}

// ---------------------------------------------------------------------------
__global__ __launch_bounds__(256) void final_kernel(
    const float* __restrict__ z, const float* __restrict__ w2,
    const float* __restrict__ b2, float* __restrict__ out)
{
    const int m = blockIdx.x * 128 + (threadIdx.x >> 1);
    const int c = threadIdx.x & 1;
    const float* zr = z + (size_t)m * 256;
    const float* wr = w2 + (size_t)c * 256;
    float s = b2[c];
    #pragma unroll 8
    for (int k = 0; k < 256; k += 4) {
        float4 zv = *(const float4*)&zr[k];
        float4 wv = *(const float4*)&wr[k];
        s += zv.x*wv.x + zv.y*wv.y + zv.z*wv.z + zv.w*wv.w;
    }
    out[(size_t)m * 2 + c] = s;
}

// ---------------------------------------------------------------------------
extern "C" void kernel_launch(void* const* d_in, const int* in_sizes, int n_in,
                              void* d_out, int out_size, void* d_ws, size_t ws_size,
                              hipStream_t stream) {
    const float* x    = (const float*)d_in[0];
    const float* fc_w = (const float*)d_in[1];
    const float* fc_b = (const float*)d_in[2];
    const float* fw   = (const float*)d_in[3];
    const float* fb   = (const float*)d_in[4];
    const float* iw   = (const float*)d_in[5];
    const float* ib   = (const float*)d_in[6];
    const float* uw   = (const float*)d_in[7];
    const float* ub   = (const float*)d_in[8];
    const float* ow   = (const float*)d_in[9];
    const float* ob   = (const float*)d_in[10];
    const float* w0   = (const float*)d_in[11];
    const float* b0   = (const float*)d_in[12];
    const float* w1   = (const float*)d_in[13];
    const float* b1   = (const float*)d_in[14];
    const float* w2   = (const float*)d_in[15];
    const float* b2   = (const float*)d_in[16];
    float* out = (float*)d_out;

    // Workspace layout is byte-identical to round 2 (keeps use_xg decision).
    float* ws = (float*)d_ws;
    size_t off = 0;
    float* h_buf  = ws + off; off += (size_t)TBR * HH;     // 33,554,432 f
    float* wx_p   = ws + off; off += 1024 * 256;           // also wx_mf
    float* wh_p   = ws + off; off += 1024 * 256;           // also wh_mf
    float* b_p    = ws + off; off += 1024;                 // also b_mf
    float* hx_buf = ws + off; off += 2 * BB * HH;          // fallback only
    float* sync_f = ws + off; off += 131072;               // flags / hx-planes
    const size_t base_f = off;
    float* xg = ws + base_f;
    const size_t need_xg = (base_f + (size_t)TBR * 1024) * sizeof(float);
    const int use_xg = (ws_size >= need_xg) ? 1 : 0;
    float* z0 = use_xg ? xg : (ws + base_f);

    // mfma-path aliases inside sync_f (32768 + 32768 + 65536 = 131072)
    unsigned* hxh   = (unsigned*)sync_f;
    unsigned* hxl   = hxh + 32768;
    int* flags_mf   = (int*)(hxl + 32768);
    int* flags_old  = (int*)sync_f;

    // zero hx ping-pong + sync region (768 KB, covers both paths)
    hipMemsetAsync(hx_buf, 0, (2 * BB * HH + 131072) * sizeof(float), stream);

    if (use_xg) {
        pack_mfma<<<1024, 256, 0, stream>>>(fw, iw, uw, ow, fb, ib, ub, ob,
                                            wx_p, wh_p, b_p);
        gemm_kernel<512, 1, 0><<<dim3(TBR / 128, 2), 256, 0, stream>>>(
            x, fc_w, fc_b, h_buf, 256);
        gemm_kernel<256, 0, 0><<<dim3(TBR / 128, 8), 256, 0, stream>>>(
            h_buf, wx_p, b_p, xg, 1024);
        recur_mfma<<<64, 256, 0, stream>>>(h_buf, xg, wh_p, hxh, hxl, flags_mf);
    } else {
        pack_kernel<<<1024, 256, 0, stream>>>(fw, iw, uw, ow, fb, ib, ub, ob,
                                              wx_p, wh_p, b_p);
        gemm_kernel<512, 1, 0><<<dim3(TBR / 128, 2), 256, 0, stream>>>(
            x, fc_w, fc_b, h_buf, 256);
        recur_kernel<<<128, 256, 0, stream>>>(h_buf, nullptr, wx_p, wh_p, b_p,
                                              hx_buf, flags_old, 0);
    }
    gemm_kernel<256, 2, 0><<<dim3(TBR / 128, 2), 256, 0, stream>>>(
        h_buf, w0, b0, z0, 256);
    gemm_kernel<256, 2, 0><<<dim3(TBR / 128, 2), 256, 0, stream>>>(
        z0, w1, b1, h_buf, 256);
    final_kernel<<<TBR / 128, 256, 0, stream>>>(h_buf, w2, b2, out);
}